// Round 2
// baseline (681.827 us; speedup 1.0000x reference)
//
#include <hip/hip_runtime.h>
#include <hip/hip_bf16.h>
#include <math.h>

#define N_NODES 40000
#define E_EDGES 640000
#define D 128
#define LN_EPS 1e-5f
#define LEAKY 0.2f

// ---------------- zero kernel: d_out (N*D floats) + deg (N floats) ----------------
__global__ __launch_bounds__(256) void k_zero(float* __restrict__ out, float* __restrict__ deg) {
    int i = blockIdx.x * 256 + threadIdx.x;
    const int n_out4 = N_NODES * D / 4;   // 1,280,000
    const int n_deg4 = N_NODES / 4;       // 10,000
    if (i < n_out4) {
        ((float4*)out)[i] = make_float4(0.f, 0.f, 0.f, 0.f);
    } else if (i < n_out4 + n_deg4) {
        ((float4*)deg)[i - n_out4] = make_float4(0.f, 0.f, 0.f, 0.f);
    }
}

// ---------------- GEMM: out_lin[N,128] = x[N,128] @ w[128,128] ----------------
#define BM 32
__global__ __launch_bounds__(256) void k_gemm(const float* __restrict__ x,
                                              const float* __restrict__ w,
                                              float* __restrict__ out) {
    __shared__ float ws[128 * 128];
    __shared__ float xs[BM * 128];
    int t = threadIdx.x;

    // stage weight (64 KB): 4096 float4 / 256 threads = 16 each, coalesced
    const float4* w4 = (const float4*)w;
    float4* ws4 = (float4*)ws;
#pragma unroll
    for (int i = 0; i < 16; i++) ws4[t + i * 256] = w4[t + i * 256];

    // stage x tile (16 KB): 1024 float4 / 256 = 4 each
    int row0 = blockIdx.x * BM;
    const float4* x4 = (const float4*)(x + (size_t)row0 * D);
    float4* xs4 = (float4*)xs;
#pragma unroll
    for (int i = 0; i < 4; i++) xs4[t + i * 256] = x4[t + i * 256];

    __syncthreads();

    int c0 = (t & 31) * 4;       // 4 consecutive output cols
    int r0 = (t >> 5) * 4;       // 4 rows
    float acc[4][4] = {};
#pragma unroll 4
    for (int k = 0; k < 128; k++) {
        float4 wv = *(const float4*)&ws[k * 128 + c0];
        float x0 = xs[(r0 + 0) * 128 + k];
        float x1 = xs[(r0 + 1) * 128 + k];
        float x2 = xs[(r0 + 2) * 128 + k];
        float x3 = xs[(r0 + 3) * 128 + k];
        acc[0][0] += x0 * wv.x; acc[0][1] += x0 * wv.y; acc[0][2] += x0 * wv.z; acc[0][3] += x0 * wv.w;
        acc[1][0] += x1 * wv.x; acc[1][1] += x1 * wv.y; acc[1][2] += x1 * wv.z; acc[1][3] += x1 * wv.w;
        acc[2][0] += x2 * wv.x; acc[2][1] += x2 * wv.y; acc[2][2] += x2 * wv.z; acc[2][3] += x2 * wv.w;
        acc[3][0] += x3 * wv.x; acc[3][1] += x3 * wv.y; acc[3][2] += x3 * wv.z; acc[3][3] += x3 * wv.w;
    }
#pragma unroll
    for (int i = 0; i < 4; i++) {
        int row = row0 + r0 + i;
        *(float4*)&out[(size_t)row * D + c0] =
            make_float4(acc[i][0], acc[i][1], acc[i][2], acc[i][3]);
    }
}

// ---------------- degree accumulation: deg[row[e]] += ew[e]*sigmoid(aw) ----------------
__global__ __launch_bounds__(256) void k_deg(const int* __restrict__ ei,
                                             const float* __restrict__ ew,
                                             const float* __restrict__ aw,
                                             float* __restrict__ deg) {
    int e = blockIdx.x * 256 + threadIdx.x;
    if (e >= E_EDGES) return;
    float sig = 1.f / (1.f + __expf(-aw[0]));
    atomicAdd(&deg[ei[e]], ew[e] * sig);
}

// ---------------- dis[n] = deg[n] > 0 ? rsqrt(deg[n]) : 0 ----------------
__global__ __launch_bounds__(256) void k_dis(const float* __restrict__ deg,
                                             float* __restrict__ dis) {
    int n = blockIdx.x * 256 + threadIdx.x;
    if (n >= N_NODES) return;
    float d = deg[n];
    dis[n] = (d > 0.f) ? rsqrtf(d) : 0.f;
}

// ---------------- scatter: one wave per edge ----------------
// accum[row] += out_lin[col] * (dis[row]*aew*dis[col])
__global__ __launch_bounds__(256) void k_scatter(const int* __restrict__ ei,
                                                 const float* __restrict__ ew,
                                                 const float* __restrict__ aw,
                                                 const float* __restrict__ dis,
                                                 const float* __restrict__ out_lin,
                                                 float* __restrict__ accum) {
    int wave = (blockIdx.x * 256 + threadIdx.x) >> 6;
    int lane = threadIdx.x & 63;
    if (wave >= E_EDGES) return;
    // uniform scalar: sigmoid of the single adaptive weight
    float sig = 1.f / (1.f + __expf(-aw[0]));
    int r = ei[wave];
    int c = ei[E_EDGES + wave];
    float norm = dis[r] * (ew[wave] * sig) * dis[c];
    float2 v = *(const float2*)&out_lin[(size_t)c * D + lane * 2];
    float* dst = &accum[(size_t)r * D + lane * 2];
    atomicAdd(dst,     v.x * norm);
    atomicAdd(dst + 1, v.y * norm);
}

// ---------------- fused bias + LayerNorm + LeakyReLU, in-place on d_out ----------------
__global__ __launch_bounds__(256) void k_ln(float* __restrict__ out,
                                            const float* __restrict__ bias,
                                            const float* __restrict__ gamma,
                                            const float* __restrict__ beta) {
    int node = (blockIdx.x * 256 + threadIdx.x) >> 6;
    int lane = threadIdx.x & 63;
    if (node >= N_NODES) return;
    float2 v = *(float2*)&out[(size_t)node * D + lane * 2];
    float2 b = *(const float2*)&bias[lane * 2];
    v.x += b.x; v.y += b.y;

    float s = v.x + v.y;
#pragma unroll
    for (int m = 1; m < 64; m <<= 1) s += __shfl_xor(s, m);
    float mu = s * (1.f / 128.f);

    float dx = v.x - mu, dy = v.y - mu;
    float q = dx * dx + dy * dy;
#pragma unroll
    for (int m = 1; m < 64; m <<= 1) q += __shfl_xor(q, m);
    float rstd = rsqrtf(q * (1.f / 128.f) + LN_EPS);

    float2 g  = *(const float2*)&gamma[lane * 2];
    float2 be = *(const float2*)&beta[lane * 2];
    float y0 = dx * rstd * g.x + be.x;
    float y1 = dy * rstd * g.y + be.y;
    y0 = (y0 >= 0.f) ? y0 : LEAKY * y0;
    y1 = (y1 >= 0.f) ? y1 : LEAKY * y1;
    *(float2*)&out[(size_t)node * D + lane * 2] = make_float2(y0, y1);
}

extern "C" void kernel_launch(void* const* d_in, const int* in_sizes, int n_in,
                              void* d_out, int out_size, void* d_ws, size_t ws_size,
                              hipStream_t stream) {
    const float* x      = (const float*)d_in[0];
    const int*   ei     = (const int*)d_in[1];
    const float* ew     = (const float*)d_in[2];
    const float* w      = (const float*)d_in[3];
    const float* aw     = (const float*)d_in[4];
    const float* bias   = (const float*)d_in[5];
    const float* gamma  = (const float*)d_in[6];
    const float* beta   = (const float*)d_in[7];
    float* out = (float*)d_out;

    float* ws_f    = (float*)d_ws;
    float* out_lin = ws_f;                       // N*128 floats
    float* deg     = ws_f + (size_t)N_NODES * D; // N floats
    float* dis     = deg + N_NODES;              // N floats

    // 1) zero d_out + deg
    {
        int total = N_NODES * D / 4 + N_NODES / 4;
        k_zero<<<(total + 255) / 256, 256, 0, stream>>>(out, deg);
    }
    // 2) out_lin = x @ w
    k_gemm<<<N_NODES / BM, 256, 0, stream>>>(x, w, out_lin);
    // 3) deg
    k_deg<<<(E_EDGES + 255) / 256, 256, 0, stream>>>(ei, ew, aw, deg);
    // 4) dis
    k_dis<<<(N_NODES + 255) / 256, 256, 0, stream>>>(deg, dis);
    // 5) scatter (one wave per edge)
    k_scatter<<<E_EDGES / 4, 256, 0, stream>>>(ei, ew, aw, dis, out_lin, out);
    // 6) bias + LN + LeakyReLU
    k_ln<<<(N_NODES + 3) / 4, 256, 0, stream>>>(out, bias, gamma, beta);
}

// Round 5
// 394.106 us; speedup vs baseline: 1.7301x; 1.7301x over previous
//
#include <hip/hip_runtime.h>
#include <hip/hip_bf16.h>
#include <math.h>

#define N_NODES 40000
#define E_EDGES 640000
#define D 128
#define LN_EPS 1e-5f
#define LEAKY 0.2f

// ---------------- zero cnt[N] (int) + deg[N] (float) ----------------
__global__ __launch_bounds__(256) void k_zero(int* __restrict__ cnt, float* __restrict__ deg) {
    int i = blockIdx.x * 256 + threadIdx.x;
    if (i < N_NODES) { cnt[i] = 0; deg[i] = 0.f; }
}

// ---------------- GEMM: out_lin[N,128] = x[N,128] @ w[128,128] ----------------
#define BM 32
__global__ __launch_bounds__(256) void k_gemm(const float* __restrict__ x,
                                              const float* __restrict__ w,
                                              float* __restrict__ out) {
    __shared__ float ws[128 * 128];
    __shared__ float xs[BM * 128];
    int t = threadIdx.x;

    const float4* w4 = (const float4*)w;
    float4* ws4 = (float4*)ws;
#pragma unroll
    for (int i = 0; i < 16; i++) ws4[t + i * 256] = w4[t + i * 256];

    int row0 = blockIdx.x * BM;
    const float4* x4 = (const float4*)(x + (size_t)row0 * D);
    float4* xs4 = (float4*)xs;
#pragma unroll
    for (int i = 0; i < 4; i++) xs4[t + i * 256] = x4[t + i * 256];

    __syncthreads();

    int c0 = (t & 31) * 4;
    int r0 = (t >> 5) * 4;
    float acc[4][4] = {};
#pragma unroll 4
    for (int k = 0; k < 128; k++) {
        float4 wv = *(const float4*)&ws[k * 128 + c0];
        float x0 = xs[(r0 + 0) * 128 + k];
        float x1 = xs[(r0 + 1) * 128 + k];
        float x2 = xs[(r0 + 2) * 128 + k];
        float x3 = xs[(r0 + 3) * 128 + k];
        acc[0][0] += x0 * wv.x; acc[0][1] += x0 * wv.y; acc[0][2] += x0 * wv.z; acc[0][3] += x0 * wv.w;
        acc[1][0] += x1 * wv.x; acc[1][1] += x1 * wv.y; acc[1][2] += x1 * wv.z; acc[1][3] += x1 * wv.w;
        acc[2][0] += x2 * wv.x; acc[2][1] += x2 * wv.y; acc[2][2] += x2 * wv.z; acc[2][3] += x2 * wv.w;
        acc[3][0] += x3 * wv.x; acc[3][1] += x3 * wv.y; acc[3][2] += x3 * wv.z; acc[3][3] += x3 * wv.w;
    }
#pragma unroll
    for (int i = 0; i < 4; i++) {
        int row = row0 + r0 + i;
        *(float4*)&out[(size_t)row * D + c0] =
            make_float4(acc[i][0], acc[i][1], acc[i][2], acc[i][3]);
    }
}

// ---------------- histogram: cnt[row]++ and deg[row] += ew*sig ----------------
__global__ __launch_bounds__(256) void k_hist(const int* __restrict__ ei,
                                              const float* __restrict__ ew,
                                              const float* __restrict__ aw,
                                              int* __restrict__ cnt,
                                              float* __restrict__ deg) {
    int e = blockIdx.x * 256 + threadIdx.x;
    if (e >= E_EDGES) return;
    float sig = 1.f / (1.f + __expf(-aw[0]));
    int r = ei[e];
    atomicAdd(&cnt[r], 1);
    atomicAdd(&deg[r], ew[e] * sig);
}

// ---------------- single-block exclusive scan of cnt -> rowstart, pos; dis = rsqrt(deg) ----------------
__global__ __launch_bounds__(1024) void k_scan(const int* __restrict__ cnt,
                                               const float* __restrict__ deg,
                                               int* __restrict__ rowstart,
                                               int* __restrict__ pos,
                                               float* __restrict__ dis) {
    __shared__ int sums[1024];
    int t = threadIdx.x;
    const int CH = 40; // 1024*40 = 40960 >= 40000
    int lo = t * CH;
    int hi = min(lo + CH, N_NODES);
    int s = 0;
    for (int i = lo; i < hi; i++) s += cnt[i];
    sums[t] = s;
    __syncthreads();
    // Hillis-Steele inclusive scan
    for (int off = 1; off < 1024; off <<= 1) {
        int v = (t >= off) ? sums[t - off] : 0;
        __syncthreads();
        sums[t] += v;
        __syncthreads();
    }
    int run = (t == 0) ? 0 : sums[t - 1];
    for (int i = lo; i < hi; i++) {
        rowstart[i] = run;
        pos[i] = run;
        run += cnt[i];
        float d = deg[i];
        dis[i] = (d > 0.f) ? rsqrtf(d) : 0.f;
    }
    if (t == 1023) rowstart[N_NODES] = sums[1023]; // == E
}

// ---------------- scatter edges into row-sorted records ----------------
// srec[p] = (col_bits, ew*sig*dis[col])
__global__ __launch_bounds__(256) void k_sort(const int* __restrict__ ei,
                                              const float* __restrict__ ew,
                                              const float* __restrict__ aw,
                                              const float* __restrict__ dis,
                                              int* __restrict__ pos,
                                              float2* __restrict__ srec) {
    int e = blockIdx.x * 256 + threadIdx.x;
    if (e >= E_EDGES) return;
    float sig = 1.f / (1.f + __expf(-aw[0]));
    int r = ei[e];
    int c = ei[E_EDGES + e];
    int p = atomicAdd(&pos[r], 1);
    srec[p] = make_float2(__int_as_float(c), ew[e] * sig * dis[c]);
}

// ---------------- pull-aggregation + bias + LN + LeakyReLU, one wave per row ----------------
__global__ __launch_bounds__(256) void k_agg(const int* __restrict__ rowstart,
                                             const float2* __restrict__ srec,
                                             const float* __restrict__ out_lin,
                                             const float* __restrict__ dis,
                                             const float* __restrict__ bias,
                                             const float* __restrict__ gamma,
                                             const float* __restrict__ beta,
                                             float* __restrict__ out) {
    int w = (blockIdx.x * 256 + threadIdx.x) >> 6;
    int lane = threadIdx.x & 63;
    if (w >= N_NODES) return;
    int s = __builtin_amdgcn_readfirstlane(rowstart[w]);
    int e = __builtin_amdgcn_readfirstlane(rowstart[w + 1]);
    float dr = dis[w];

    float2 acc = make_float2(0.f, 0.f);
    for (int i = s; i < e; i++) {
        float2 rec = srec[i];                 // wave-uniform 8B load
        int c = __float_as_int(rec.x);
        float v = rec.y;
        const float2 t = *(const float2*)&out_lin[(size_t)c * D + lane * 2];
        acc.x += t.x * v;
        acc.y += t.y * v;
    }
    acc.x *= dr; acc.y *= dr;

    float2 b = *(const float2*)&bias[lane * 2];
    acc.x += b.x; acc.y += b.y;

    float sm = acc.x + acc.y;
#pragma unroll
    for (int m = 1; m < 64; m <<= 1) sm += __shfl_xor(sm, m);
    float mu = sm * (1.f / 128.f);

    float dx = acc.x - mu, dy = acc.y - mu;
    float q = dx * dx + dy * dy;
#pragma unroll
    for (int m = 1; m < 64; m <<= 1) q += __shfl_xor(q, m);
    float rstd = rsqrtf(q * (1.f / 128.f) + LN_EPS);

    float2 g  = *(const float2*)&gamma[lane * 2];
    float2 be = *(const float2*)&beta[lane * 2];
    float y0 = dx * rstd * g.x + be.x;
    float y1 = dy * rstd * g.y + be.y;
    y0 = (y0 >= 0.f) ? y0 : LEAKY * y0;
    y1 = (y1 >= 0.f) ? y1 : LEAKY * y1;
    *(float2*)&out[(size_t)w * D + lane * 2] = make_float2(y0, y1);
}

extern "C" void kernel_launch(void* const* d_in, const int* in_sizes, int n_in,
                              void* d_out, int out_size, void* d_ws, size_t ws_size,
                              hipStream_t stream) {
    const float* x      = (const float*)d_in[0];
    const int*   ei     = (const int*)d_in[1];
    const float* ew     = (const float*)d_in[2];
    const float* w      = (const float*)d_in[3];
    const float* aw     = (const float*)d_in[4];
    const float* bias   = (const float*)d_in[5];
    const float* gamma  = (const float*)d_in[6];
    const float* beta   = (const float*)d_in[7];
    float* out = (float*)d_out;

    // workspace layout
    char* p = (char*)d_ws;
    float* out_lin  = (float*)p;            p += (size_t)N_NODES * D * 4;  // 20.48 MB
    float* deg      = (float*)p;            p += N_NODES * 4;
    float* dis      = (float*)p;            p += N_NODES * 4;
    int*   cnt      = (int*)p;              p += N_NODES * 4;
    int*   rowstart = (int*)p;              p += (N_NODES + 1) * 4;
    int*   pos      = (int*)p;              p += N_NODES * 4;
    float2* srec    = (float2*)((((uintptr_t)p) + 15) & ~(uintptr_t)15); // 5.12 MB

    // 1) zero cnt + deg
    k_zero<<<(N_NODES + 255) / 256, 256, 0, stream>>>(cnt, deg);
    // 2) out_lin = x @ w
    k_gemm<<<N_NODES / BM, 256, 0, stream>>>(x, w, out_lin);
    // 3) histogram + weighted degree
    k_hist<<<(E_EDGES + 255) / 256, 256, 0, stream>>>(ei, ew, aw, cnt, deg);
    // 4) prefix scan + dis
    k_scan<<<1, 1024, 0, stream>>>(cnt, deg, rowstart, pos, dis);
    // 5) counting-sort edges by row
    k_sort<<<(E_EDGES + 255) / 256, 256, 0, stream>>>(ei, ew, aw, dis, pos, srec);
    // 6) fused pull-aggregation + bias + LN + LeakyReLU
    k_agg<<<(N_NODES + 3) / 4, 256, 0, stream>>>(rowstart, srec, out_lin, dis,
                                                 bias, gamma, beta, out);
}

// Round 7
// 259.132 us; speedup vs baseline: 2.6312x; 1.5209x over previous
//
#include <hip/hip_runtime.h>
#include <hip/hip_bf16.h>
#include <math.h>

#define N_NODES 40000
#define E_EDGES 640000
#define D 128
#define LN_EPS 1e-5f
#define LEAKY 0.2f
#define NB 157   // ceil(40000/256)

// ---------------- zero cnt[N] (int) + deg[N] (float) ----------------
__global__ __launch_bounds__(256) void k_zero(int* __restrict__ cnt, float* __restrict__ deg) {
    int i = blockIdx.x * 256 + threadIdx.x;
    if (i < N_NODES) { cnt[i] = 0; deg[i] = 0.f; }
}

// ---------------- GEMM: out_lin[N,128] = x[N,128] @ w[128,128] ----------------
#define BM 32
__global__ __launch_bounds__(256) void k_gemm(const float* __restrict__ x,
                                              const float* __restrict__ w,
                                              float* __restrict__ out) {
    __shared__ float ws[128 * 128];
    __shared__ float xs[BM * 128];
    int t = threadIdx.x;

    const float4* w4 = (const float4*)w;
    float4* ws4 = (float4*)ws;
#pragma unroll
    for (int i = 0; i < 16; i++) ws4[t + i * 256] = w4[t + i * 256];

    int row0 = blockIdx.x * BM;
    const float4* x4 = (const float4*)(x + (size_t)row0 * D);
    float4* xs4 = (float4*)xs;
#pragma unroll
    for (int i = 0; i < 4; i++) xs4[t + i * 256] = x4[t + i * 256];

    __syncthreads();

    int c0 = (t & 31) * 4;
    int r0 = (t >> 5) * 4;
    float acc[4][4] = {};
#pragma unroll 4
    for (int k = 0; k < 128; k++) {
        float4 wv = *(const float4*)&ws[k * 128 + c0];
        float x0 = xs[(r0 + 0) * 128 + k];
        float x1 = xs[(r0 + 1) * 128 + k];
        float x2 = xs[(r0 + 2) * 128 + k];
        float x3 = xs[(r0 + 3) * 128 + k];
        acc[0][0] += x0 * wv.x; acc[0][1] += x0 * wv.y; acc[0][2] += x0 * wv.z; acc[0][3] += x0 * wv.w;
        acc[1][0] += x1 * wv.x; acc[1][1] += x1 * wv.y; acc[1][2] += x1 * wv.z; acc[1][3] += x1 * wv.w;
        acc[2][0] += x2 * wv.x; acc[2][1] += x2 * wv.y; acc[2][2] += x2 * wv.z; acc[2][3] += x2 * wv.w;
        acc[3][0] += x3 * wv.x; acc[3][1] += x3 * wv.y; acc[3][2] += x3 * wv.z; acc[3][3] += x3 * wv.w;
    }
#pragma unroll
    for (int i = 0; i < 4; i++) {
        int row = row0 + r0 + i;
        *(float4*)&out[(size_t)row * D + c0] =
            make_float4(acc[i][0], acc[i][1], acc[i][2], acc[i][3]);
    }
}

// ---------------- histogram: cnt[row]++ and deg[row] += ew*sig ----------------
__global__ __launch_bounds__(256) void k_hist(const int* __restrict__ ei,
                                              const float* __restrict__ ew,
                                              const float* __restrict__ aw,
                                              int* __restrict__ cnt,
                                              float* __restrict__ deg) {
    int e = blockIdx.x * 256 + threadIdx.x;
    if (e >= E_EDGES) return;
    float sig = 1.f / (1.f + __expf(-aw[0]));
    int r = ei[e];
    atomicAdd(&cnt[r], 1);
    atomicAdd(&deg[r], ew[e] * sig);
}

// ---------------- 3-phase device-wide exclusive scan of cnt ----------------
// A: per-block sums
__global__ __launch_bounds__(256) void k_scanA(const int* __restrict__ cnt,
                                               int* __restrict__ bsum) {
    __shared__ int red[256];
    int t = threadIdx.x;
    int i = blockIdx.x * 256 + t;
    red[t] = (i < N_NODES) ? cnt[i] : 0;
    __syncthreads();
    for (int off = 128; off > 0; off >>= 1) {
        if (t < off) red[t] += red[t + off];
        __syncthreads();
    }
    if (t == 0) bsum[blockIdx.x] = red[0];
}

// B: scan the NB block sums (single small block)
__global__ __launch_bounds__(256) void k_scanB(const int* __restrict__ bsum,
                                               int* __restrict__ boff,
                                               int* __restrict__ rowstart) {
    __shared__ int s[256];
    int t = threadIdx.x;
    int v = (t < NB) ? bsum[t] : 0;
    s[t] = v;
    __syncthreads();
    for (int off = 1; off < 256; off <<= 1) {
        int u = (t >= off) ? s[t - off] : 0;
        __syncthreads();
        s[t] += u;
        __syncthreads();
    }
    if (t < NB) boff[t] = s[t] - v;   // exclusive
    if (t == 0) rowstart[N_NODES] = E_EDGES;
}

// C: local exclusive scan + block offset; also dis = rsqrt(deg)
__global__ __launch_bounds__(256) void k_scanC(const int* __restrict__ cnt,
                                               const int* __restrict__ boff,
                                               const float* __restrict__ deg,
                                               int* __restrict__ rowstart,
                                               int* __restrict__ pos,
                                               float* __restrict__ dis) {
    __shared__ int s[256];
    int t = threadIdx.x;
    int i = blockIdx.x * 256 + t;
    int v = (i < N_NODES) ? cnt[i] : 0;
    s[t] = v;
    __syncthreads();
    for (int off = 1; off < 256; off <<= 1) {
        int u = (t >= off) ? s[t - off] : 0;
        __syncthreads();
        s[t] += u;
        __syncthreads();
    }
    if (i < N_NODES) {
        int ex = boff[blockIdx.x] + s[t] - v;
        rowstart[i] = ex;
        pos[i] = ex;
        float d = deg[i];
        dis[i] = (d > 0.f) ? rsqrtf(d) : 0.f;
    }
}

// ---------------- scatter edges into row-sorted records ----------------
// srec[p] = (col_bits, ew*sig*dis[col])
__global__ __launch_bounds__(256) void k_sort(const int* __restrict__ ei,
                                              const float* __restrict__ ew,
                                              const float* __restrict__ aw,
                                              const float* __restrict__ dis,
                                              int* __restrict__ pos,
                                              float2* __restrict__ srec) {
    int e = blockIdx.x * 256 + threadIdx.x;
    if (e >= E_EDGES) return;
    float sig = 1.f / (1.f + __expf(-aw[0]));
    int r = ei[e];
    int c = ei[E_EDGES + e];
    int p = atomicAdd(&pos[r], 1);
    srec[p] = make_float2(__int_as_float(c), ew[e] * sig * dis[c]);
}

// ---------------- pull-aggregation + bias + LN + LeakyReLU, one wave per row ----------------
__global__ __launch_bounds__(256) void k_agg(const int* __restrict__ rowstart,
                                             const float2* __restrict__ srec,
                                             const float* __restrict__ out_lin,
                                             const float* __restrict__ dis,
                                             const float* __restrict__ bias,
                                             const float* __restrict__ gamma,
                                             const float* __restrict__ beta,
                                             float* __restrict__ out) {
    int w = (blockIdx.x * 256 + threadIdx.x) >> 6;
    int lane = threadIdx.x & 63;
    if (w >= N_NODES) return;
    int s = __builtin_amdgcn_readfirstlane(rowstart[w]);
    int e = __builtin_amdgcn_readfirstlane(rowstart[w + 1]);
    float dr = dis[w];

    float2 acc = make_float2(0.f, 0.f);
    for (int i = s; i < e; i++) {
        float2 rec = srec[i];                 // wave-uniform 8B load
        int c = __float_as_int(rec.x);
        float v = rec.y;
        const float2 t = *(const float2*)&out_lin[(size_t)c * D + lane * 2];
        acc.x += t.x * v;
        acc.y += t.y * v;
    }
    acc.x *= dr; acc.y *= dr;

    float2 b = *(const float2*)&bias[lane * 2];
    acc.x += b.x; acc.y += b.y;

    float sm = acc.x + acc.y;
#pragma unroll
    for (int m = 1; m < 64; m <<= 1) sm += __shfl_xor(sm, m);
    float mu = sm * (1.f / 128.f);

    float dx = acc.x - mu, dy = acc.y - mu;
    float q = dx * dx + dy * dy;
#pragma unroll
    for (int m = 1; m < 64; m <<= 1) q += __shfl_xor(q, m);
    float rstd = rsqrtf(q * (1.f / 128.f) + LN_EPS);

    float2 g  = *(const float2*)&gamma[lane * 2];
    float2 be = *(const float2*)&beta[lane * 2];
    float y0 = dx * rstd * g.x + be.x;
    float y1 = dy * rstd * g.y + be.y;
    y0 = (y0 >= 0.f) ? y0 : LEAKY * y0;
    y1 = (y1 >= 0.f) ? y1 : LEAKY * y1;
    *(float2*)&out[(size_t)w * D + lane * 2] = make_float2(y0, y1);
}

extern "C" void kernel_launch(void* const* d_in, const int* in_sizes, int n_in,
                              void* d_out, int out_size, void* d_ws, size_t ws_size,
                              hipStream_t stream) {
    const float* x      = (const float*)d_in[0];
    const int*   ei     = (const int*)d_in[1];
    const float* ew     = (const float*)d_in[2];
    const float* w      = (const float*)d_in[3];
    const float* aw     = (const float*)d_in[4];
    const float* bias   = (const float*)d_in[5];
    const float* gamma  = (const float*)d_in[6];
    const float* beta   = (const float*)d_in[7];
    float* out = (float*)d_out;

    // workspace layout
    char* p = (char*)d_ws;
    float* out_lin  = (float*)p;            p += (size_t)N_NODES * D * 4;  // 20.48 MB
    float* deg      = (float*)p;            p += N_NODES * 4;
    float* dis      = (float*)p;            p += N_NODES * 4;
    int*   cnt      = (int*)p;              p += N_NODES * 4;
    int*   rowstart = (int*)p;              p += (N_NODES + 1) * 4;
    int*   pos      = (int*)p;              p += N_NODES * 4;
    int*   bsum     = (int*)p;              p += NB * 4;
    int*   boff     = (int*)p;              p += NB * 4;
    float2* srec    = (float2*)((((uintptr_t)p) + 15) & ~(uintptr_t)15); // 5.12 MB

    // 1) zero cnt + deg
    k_zero<<<NB, 256, 0, stream>>>(cnt, deg);
    // 2) out_lin = x @ w
    k_gemm<<<N_NODES / BM, 256, 0, stream>>>(x, w, out_lin);
    // 3) histogram + weighted degree
    k_hist<<<(E_EDGES + 255) / 256, 256, 0, stream>>>(ei, ew, aw, cnt, deg);
    // 4) 3-phase scan + dis
    k_scanA<<<NB, 256, 0, stream>>>(cnt, bsum);
    k_scanB<<<1, 256, 0, stream>>>(bsum, boff, rowstart);
    k_scanC<<<NB, 256, 0, stream>>>(cnt, boff, deg, rowstart, pos, dis);
    // 5) counting-sort edges by row
    k_sort<<<(E_EDGES + 255) / 256, 256, 0, stream>>>(ei, ew, aw, dis, pos, srec);
    // 6) fused pull-aggregation + bias + LN + LeakyReLU
    k_agg<<<(N_NODES + 3) / 4, 256, 0, stream>>>(rowstart, srec, out_lin, dis,
                                                 bias, gamma, beta, out);
}

// Round 8
// 215.405 us; speedup vs baseline: 3.1653x; 1.2030x over previous
//
#include <hip/hip_runtime.h>
#include <hip/hip_bf16.h>
#include <math.h>

#define N_NODES 40000
#define E_EDGES 640000
#define D 128
#define LN_EPS 1e-5f
#define LEAKY 0.2f
#define NB 157   // ceil(40000/256)

// ---------------- zero cnt[N] ----------------
__global__ __launch_bounds__(256) void k_zero(int* __restrict__ cnt) {
    int i = blockIdx.x * 256 + threadIdx.x;
    if (i < N_NODES) cnt[i] = 0;
}

// ---------------- GEMM: out_lin[N,128] = x[N,128] @ w[128,128] ----------------
#define BM 32
__global__ __launch_bounds__(256) void k_gemm(const float* __restrict__ x,
                                              const float* __restrict__ w,
                                              float* __restrict__ out) {
    __shared__ float ws[128 * 128];
    __shared__ float xs[BM * 128];
    int t = threadIdx.x;

    const float4* w4 = (const float4*)w;
    float4* ws4 = (float4*)ws;
#pragma unroll
    for (int i = 0; i < 16; i++) ws4[t + i * 256] = w4[t + i * 256];

    int row0 = blockIdx.x * BM;
    const float4* x4 = (const float4*)(x + (size_t)row0 * D);
    float4* xs4 = (float4*)xs;
#pragma unroll
    for (int i = 0; i < 4; i++) xs4[t + i * 256] = x4[t + i * 256];

    __syncthreads();

    int c0 = (t & 31) * 4;
    int r0 = (t >> 5) * 4;
    float acc[4][4] = {};
#pragma unroll 4
    for (int k = 0; k < 128; k++) {
        float4 wv = *(const float4*)&ws[k * 128 + c0];
        float x0 = xs[(r0 + 0) * 128 + k];
        float x1 = xs[(r0 + 1) * 128 + k];
        float x2 = xs[(r0 + 2) * 128 + k];
        float x3 = xs[(r0 + 3) * 128 + k];
        acc[0][0] += x0 * wv.x; acc[0][1] += x0 * wv.y; acc[0][2] += x0 * wv.z; acc[0][3] += x0 * wv.w;
        acc[1][0] += x1 * wv.x; acc[1][1] += x1 * wv.y; acc[1][2] += x1 * wv.z; acc[1][3] += x1 * wv.w;
        acc[2][0] += x2 * wv.x; acc[2][1] += x2 * wv.y; acc[2][2] += x2 * wv.z; acc[2][3] += x2 * wv.w;
        acc[3][0] += x3 * wv.x; acc[3][1] += x3 * wv.y; acc[3][2] += x3 * wv.z; acc[3][3] += x3 * wv.w;
    }
#pragma unroll
    for (int i = 0; i < 4; i++) {
        int row = row0 + r0 + i;
        *(float4*)&out[(size_t)row * D + c0] =
            make_float4(acc[i][0], acc[i][1], acc[i][2], acc[i][3]);
    }
}

// ---------------- count + stable rank: rank[e] = cnt[row]++ ----------------
__global__ __launch_bounds__(256) void k_cnt(const int* __restrict__ ei,
                                             int* __restrict__ cnt,
                                             int* __restrict__ rank) {
    int e = blockIdx.x * 256 + threadIdx.x;
    if (e >= E_EDGES) return;
    rank[e] = atomicAdd(&cnt[ei[e]], 1);
}

// ---------------- 3-phase device-wide exclusive scan of cnt ----------------
__global__ __launch_bounds__(256) void k_scanA(const int* __restrict__ cnt,
                                               int* __restrict__ bsum) {
    __shared__ int red[256];
    int t = threadIdx.x;
    int i = blockIdx.x * 256 + t;
    red[t] = (i < N_NODES) ? cnt[i] : 0;
    __syncthreads();
    for (int off = 128; off > 0; off >>= 1) {
        if (t < off) red[t] += red[t + off];
        __syncthreads();
    }
    if (t == 0) bsum[blockIdx.x] = red[0];
}

__global__ __launch_bounds__(256) void k_scanB(const int* __restrict__ bsum,
                                               int* __restrict__ boff,
                                               int* __restrict__ rowstart) {
    __shared__ int s[256];
    int t = threadIdx.x;
    int v = (t < NB) ? bsum[t] : 0;
    s[t] = v;
    __syncthreads();
    for (int off = 1; off < 256; off <<= 1) {
        int u = (t >= off) ? s[t - off] : 0;
        __syncthreads();
        s[t] += u;
        __syncthreads();
    }
    if (t < NB) boff[t] = s[t] - v;   // exclusive
    if (t == 0) rowstart[N_NODES] = E_EDGES;
}

__global__ __launch_bounds__(256) void k_scanC(const int* __restrict__ cnt,
                                               const int* __restrict__ boff,
                                               int* __restrict__ rowstart) {
    __shared__ int s[256];
    int t = threadIdx.x;
    int i = blockIdx.x * 256 + t;
    int v = (i < N_NODES) ? cnt[i] : 0;
    s[t] = v;
    __syncthreads();
    for (int off = 1; off < 256; off <<= 1) {
        int u = (t >= off) ? s[t - off] : 0;
        __syncthreads();
        s[t] += u;
        __syncthreads();
    }
    if (i < N_NODES) rowstart[i] = boff[blockIdx.x] + s[t] - v;
}

// ---------------- atomic-free scatter into row-sorted records ----------------
// srec[rowstart[r] + rank[e]] = (col_bits, ew*sig)
__global__ __launch_bounds__(256) void k_scat(const int* __restrict__ ei,
                                              const float* __restrict__ ew,
                                              const float* __restrict__ aw,
                                              const int* __restrict__ rowstart,
                                              const int* __restrict__ rank,
                                              float2* __restrict__ srec) {
    int e = blockIdx.x * 256 + threadIdx.x;
    if (e >= E_EDGES) return;
    float sig = 1.f / (1.f + __expf(-aw[0]));
    int r = ei[e];
    int c = ei[E_EDGES + e];
    int slot = rowstart[r] + rank[e];
    srec[slot] = make_float2(__int_as_float(c), ew[e] * sig);
}

// ---------------- deg from sorted records (atomic-free) + dis = rsqrt ----------------
__global__ __launch_bounds__(256) void k_degdis(const int* __restrict__ rowstart,
                                                const float2* __restrict__ srec,
                                                float* __restrict__ dis) {
    int i = blockIdx.x * 256 + threadIdx.x;
    if (i >= N_NODES) return;
    int s = rowstart[i];
    int e = rowstart[i + 1];
    float d = 0.f;
    for (int j = s; j < e; j++) d += srec[j].y;
    dis[i] = (d > 0.f) ? rsqrtf(d) : 0.f;
}

// ---------------- pull-aggregation + bias + LN + LeakyReLU, one wave per row ----------------
__global__ __launch_bounds__(256) void k_agg(const int* __restrict__ rowstart,
                                             const float2* __restrict__ srec,
                                             const float* __restrict__ out_lin,
                                             const float* __restrict__ dis,
                                             const float* __restrict__ bias,
                                             const float* __restrict__ gamma,
                                             const float* __restrict__ beta,
                                             float* __restrict__ out) {
    int w = (blockIdx.x * 256 + threadIdx.x) >> 6;
    int lane = threadIdx.x & 63;
    if (w >= N_NODES) return;
    int s = __builtin_amdgcn_readfirstlane(rowstart[w]);
    int e = __builtin_amdgcn_readfirstlane(rowstart[w + 1]);
    float dr = dis[w];

    float2 acc = make_float2(0.f, 0.f);
    for (int i = s; i < e; i++) {
        float2 rec = srec[i];                 // wave-uniform 8B load
        int c = __float_as_int(rec.x);
        float v = rec.y * dis[c];             // aew * dis[col] (uniform broadcast load)
        const float2 t = *(const float2*)&out_lin[(size_t)c * D + lane * 2];
        acc.x += t.x * v;
        acc.y += t.y * v;
    }
    acc.x *= dr; acc.y *= dr;

    float2 b = *(const float2*)&bias[lane * 2];
    acc.x += b.x; acc.y += b.y;

    float sm = acc.x + acc.y;
#pragma unroll
    for (int m = 1; m < 64; m <<= 1) sm += __shfl_xor(sm, m);
    float mu = sm * (1.f / 128.f);

    float dx = acc.x - mu, dy = acc.y - mu;
    float q = dx * dx + dy * dy;
#pragma unroll
    for (int m = 1; m < 64; m <<= 1) q += __shfl_xor(q, m);
    float rstd = rsqrtf(q * (1.f / 128.f) + LN_EPS);

    float2 g  = *(const float2*)&gamma[lane * 2];
    float2 be = *(const float2*)&beta[lane * 2];
    float y0 = dx * rstd * g.x + be.x;
    float y1 = dy * rstd * g.y + be.y;
    y0 = (y0 >= 0.f) ? y0 : LEAKY * y0;
    y1 = (y1 >= 0.f) ? y1 : LEAKY * y1;
    *(float2*)&out[(size_t)w * D + lane * 2] = make_float2(y0, y1);
}

extern "C" void kernel_launch(void* const* d_in, const int* in_sizes, int n_in,
                              void* d_out, int out_size, void* d_ws, size_t ws_size,
                              hipStream_t stream) {
    const float* x      = (const float*)d_in[0];
    const int*   ei     = (const int*)d_in[1];
    const float* ew     = (const float*)d_in[2];
    const float* w      = (const float*)d_in[3];
    const float* aw     = (const float*)d_in[4];
    const float* bias   = (const float*)d_in[5];
    const float* gamma  = (const float*)d_in[6];
    const float* beta   = (const float*)d_in[7];
    float* out = (float*)d_out;

    // workspace layout
    char* p = (char*)d_ws;
    float* out_lin  = (float*)p;            p += (size_t)N_NODES * D * 4;  // 20.48 MB
    float* dis      = (float*)p;            p += N_NODES * 4;
    int*   cnt      = (int*)p;              p += N_NODES * 4;
    int*   rowstart = (int*)p;              p += (N_NODES + 1) * 4;
    int*   rank     = (int*)p;              p += (size_t)E_EDGES * 4;      // 2.56 MB
    int*   bsum     = (int*)p;              p += NB * 4;
    int*   boff     = (int*)p;              p += NB * 4;
    float2* srec    = (float2*)((((uintptr_t)p) + 15) & ~(uintptr_t)15);   // 5.12 MB

    // 1) zero cnt
    k_zero<<<NB, 256, 0, stream>>>(cnt);
    // 2) out_lin = x @ w
    k_gemm<<<N_NODES / BM, 256, 0, stream>>>(x, w, out_lin);
    // 3) count + per-edge rank (only remaining scattered atomics)
    k_cnt<<<(E_EDGES + 255) / 256, 256, 0, stream>>>(ei, cnt, rank);
    // 4) 3-phase scan -> rowstart
    k_scanA<<<NB, 256, 0, stream>>>(cnt, bsum);
    k_scanB<<<1, 256, 0, stream>>>(bsum, boff, rowstart);
    k_scanC<<<NB, 256, 0, stream>>>(cnt, boff, rowstart);
    // 5) atomic-free scatter into sorted records
    k_scat<<<(E_EDGES + 255) / 256, 256, 0, stream>>>(ei, ew, aw, rowstart, rank, srec);
    // 6) deg + dis from sorted records (atomic-free)
    k_degdis<<<NB, 256, 0, stream>>>(rowstart, srec, dis);
    // 7) fused pull-aggregation + bias + LN + LeakyReLU
    k_agg<<<(N_NODES + 3) / 4, 256, 0, stream>>>(rowstart, srec, out_lin, dis,
                                                 bias, gamma, beta, out);
}

// Round 10
// 211.294 us; speedup vs baseline: 3.2269x; 1.0195x over previous
//
#include <hip/hip_runtime.h>
#include <hip/hip_bf16.h>
#include <math.h>

#define N_NODES 40000
#define E_EDGES 640000
#define D 128
#define LN_EPS 1e-5f
#define LEAKY 0.2f
#define NB 157   // ceil(40000/256)

// ---------------- GEMM: out_lin[N,128] = bf16(x[N,128] @ w[128,128]); also zeros cnt ----------------
#define BM 32
__global__ __launch_bounds__(256) void k_gemm(const float* __restrict__ x,
                                              const float* __restrict__ w,
                                              __hip_bfloat16* __restrict__ outb,
                                              int* __restrict__ cnt) {
    // fused: zero cnt[] (grid is 1250 blocks ≫ NB)
    int gid = blockIdx.x * 256 + threadIdx.x;
    if (gid < N_NODES) cnt[gid] = 0;

    __shared__ float ws[128 * 128];
    __shared__ float xs[BM * 128];
    int t = threadIdx.x;

    const float4* w4 = (const float4*)w;
    float4* ws4 = (float4*)ws;
#pragma unroll
    for (int i = 0; i < 16; i++) ws4[t + i * 256] = w4[t + i * 256];

    int row0 = blockIdx.x * BM;
    const float4* x4 = (const float4*)(x + (size_t)row0 * D);
    float4* xs4 = (float4*)xs;
#pragma unroll
    for (int i = 0; i < 4; i++) xs4[t + i * 256] = x4[t + i * 256];

    __syncthreads();

    int c0 = (t & 31) * 4;
    int r0 = (t >> 5) * 4;
    float acc[4][4] = {};
#pragma unroll 4
    for (int k = 0; k < 128; k++) {
        float4 wv = *(const float4*)&ws[k * 128 + c0];
        float x0 = xs[(r0 + 0) * 128 + k];
        float x1 = xs[(r0 + 1) * 128 + k];
        float x2 = xs[(r0 + 2) * 128 + k];
        float x3 = xs[(r0 + 3) * 128 + k];
        acc[0][0] += x0 * wv.x; acc[0][1] += x0 * wv.y; acc[0][2] += x0 * wv.z; acc[0][3] += x0 * wv.w;
        acc[1][0] += x1 * wv.x; acc[1][1] += x1 * wv.y; acc[1][2] += x1 * wv.z; acc[1][3] += x1 * wv.w;
        acc[2][0] += x2 * wv.x; acc[2][1] += x2 * wv.y; acc[2][2] += x2 * wv.z; acc[2][3] += x2 * wv.w;
        acc[3][0] += x3 * wv.x; acc[3][1] += x3 * wv.y; acc[3][2] += x3 * wv.z; acc[3][3] += x3 * wv.w;
    }
#pragma unroll
    for (int i = 0; i < 4; i++) {
        int row = row0 + r0 + i;
        __hip_bfloat162 p0 = __float22bfloat162_rn(make_float2(acc[i][0], acc[i][1]));
        __hip_bfloat162 p1 = __float22bfloat162_rn(make_float2(acc[i][2], acc[i][3]));
        uint2 pk;
        pk.x = *(unsigned int*)&p0;
        pk.y = *(unsigned int*)&p1;
        *(uint2*)&outb[(size_t)row * D + c0] = pk;
    }
}

// ---------------- count + stable rank: rank[e] = cnt[row]++ ----------------
__global__ __launch_bounds__(256) void k_cnt(const int* __restrict__ ei,
                                             int* __restrict__ cnt,
                                             int* __restrict__ rank) {
    int e = blockIdx.x * 256 + threadIdx.x;
    if (e >= E_EDGES) return;
    rank[e] = atomicAdd(&cnt[ei[e]], 1);
}

// ---------------- 3-phase device-wide exclusive scan of cnt ----------------
__global__ __launch_bounds__(256) void k_scanA(const int* __restrict__ cnt,
                                               int* __restrict__ bsum) {
    __shared__ int red[256];
    int t = threadIdx.x;
    int i = blockIdx.x * 256 + t;
    red[t] = (i < N_NODES) ? cnt[i] : 0;
    __syncthreads();
    for (int off = 128; off > 0; off >>= 1) {
        if (t < off) red[t] += red[t + off];
        __syncthreads();
    }
    if (t == 0) bsum[blockIdx.x] = red[0];
}

__global__ __launch_bounds__(256) void k_scanB(const int* __restrict__ bsum,
                                               int* __restrict__ boff,
                                               int* __restrict__ rowstart) {
    __shared__ int s[256];
    int t = threadIdx.x;
    int v = (t < NB) ? bsum[t] : 0;
    s[t] = v;
    __syncthreads();
    for (int off = 1; off < 256; off <<= 1) {
        int u = (t >= off) ? s[t - off] : 0;
        __syncthreads();
        s[t] += u;
        __syncthreads();
    }
    if (t < NB) boff[t] = s[t] - v;   // exclusive
    if (t == 0) rowstart[N_NODES] = E_EDGES;
}

__global__ __launch_bounds__(256) void k_scanC(const int* __restrict__ cnt,
                                               const int* __restrict__ boff,
                                               int* __restrict__ rowstart) {
    __shared__ int s[256];
    int t = threadIdx.x;
    int i = blockIdx.x * 256 + t;
    int v = (i < N_NODES) ? cnt[i] : 0;
    s[t] = v;
    __syncthreads();
    for (int off = 1; off < 256; off <<= 1) {
        int u = (t >= off) ? s[t - off] : 0;
        __syncthreads();
        s[t] += u;
        __syncthreads();
    }
    if (i < N_NODES) rowstart[i] = boff[blockIdx.x] + s[t] - v;
}

// ---------------- atomic-free scatter into row-sorted records ----------------
// srec[rowstart[r] + rank[e]] = (col_bits, ew*sig)
__global__ __launch_bounds__(256) void k_scat(const int* __restrict__ ei,
                                              const float* __restrict__ ew,
                                              const float* __restrict__ aw,
                                              const int* __restrict__ rowstart,
                                              const int* __restrict__ rank,
                                              float2* __restrict__ srec) {
    int e = blockIdx.x * 256 + threadIdx.x;
    if (e >= E_EDGES) return;
    float sig = 1.f / (1.f + __expf(-aw[0]));
    int r = ei[e];
    int c = ei[E_EDGES + e];
    int slot = rowstart[r] + rank[e];
    srec[slot] = make_float2(__int_as_float(c), ew[e] * sig);
}

// ---------------- deg from sorted records (atomic-free) + dis = rsqrt ----------------
__global__ __launch_bounds__(256) void k_degdis(const int* __restrict__ rowstart,
                                                const float2* __restrict__ srec,
                                                float* __restrict__ dis) {
    int i = blockIdx.x * 256 + threadIdx.x;
    if (i >= N_NODES) return;
    int s = rowstart[i];
    int e = rowstart[i + 1];
    float d = 0.f;
    for (int j = s; j < e; j++) d += srec[j].y;
    dis[i] = (d > 0.f) ? rsqrtf(d) : 0.f;
}

// ---------------- pull-aggregation + bias + LN + LeakyReLU, one wave per row ----------------
__global__ __launch_bounds__(256) void k_agg(const int* __restrict__ rowstart,
                                             const float2* __restrict__ srec,
                                             const __hip_bfloat162* __restrict__ lin2,
                                             const float* __restrict__ dis,
                                             const float* __restrict__ bias,
                                             const float* __restrict__ gamma,
                                             const float* __restrict__ beta,
                                             float* __restrict__ out) {
    int w = (blockIdx.x * 256 + threadIdx.x) >> 6;
    int lane = threadIdx.x & 63;
    if (w >= N_NODES) return;
    int s = __builtin_amdgcn_readfirstlane(rowstart[w]);
    int e = __builtin_amdgcn_readfirstlane(rowstart[w + 1]);
    float dr = dis[w];

    float2 acc = make_float2(0.f, 0.f);
    for (int i = s; i < e; i++) {
        float2 rec = srec[i];                 // wave-uniform 8B load
        int c = __float_as_int(rec.x);
        float v = rec.y * dis[c];             // aew * dis[col] (uniform broadcast load)
        __hip_bfloat162 t = lin2[(size_t)c * 64 + lane];   // 4B/lane, 256B/wave coalesced
        float2 tf = __bfloat1622float2(t);
        acc.x += tf.x * v;
        acc.y += tf.y * v;
    }
    acc.x *= dr; acc.y *= dr;

    float2 b = *(const float2*)&bias[lane * 2];
    acc.x += b.x; acc.y += b.y;

    float sm = acc.x + acc.y;
#pragma unroll
    for (int m = 1; m < 64; m <<= 1) sm += __shfl_xor(sm, m);
    float mu = sm * (1.f / 128.f);

    float dx = acc.x - mu, dy = acc.y - mu;
    float q = dx * dx + dy * dy;
#pragma unroll
    for (int m = 1; m < 64; m <<= 1) q += __shfl_xor(q, m);
    float rstd = rsqrtf(q * (1.f / 128.f) + LN_EPS);

    float2 g  = *(const float2*)&gamma[lane * 2];
    float2 be = *(const float2*)&beta[lane * 2];
    float y0 = dx * rstd * g.x + be.x;
    float y1 = dy * rstd * g.y + be.y;
    y0 = (y0 >= 0.f) ? y0 : LEAKY * y0;
    y1 = (y1 >= 0.f) ? y1 : LEAKY * y1;
    *(float2*)&out[(size_t)w * D + lane * 2] = make_float2(y0, y1);
}

extern "C" void kernel_launch(void* const* d_in, const int* in_sizes, int n_in,
                              void* d_out, int out_size, void* d_ws, size_t ws_size,
                              hipStream_t stream) {
    const float* x      = (const float*)d_in[0];
    const int*   ei     = (const int*)d_in[1];
    const float* ew     = (const float*)d_in[2];
    const float* w      = (const float*)d_in[3];
    const float* aw     = (const float*)d_in[4];
    const float* bias   = (const float*)d_in[5];
    const float* gamma  = (const float*)d_in[6];
    const float* beta   = (const float*)d_in[7];
    float* out = (float*)d_out;

    // workspace layout
    char* p = (char*)d_ws;
    __hip_bfloat16* out_lin = (__hip_bfloat16*)p; p += (size_t)N_NODES * D * 2; // 10.24 MB
    float* dis      = (float*)p;            p += N_NODES * 4;
    int*   cnt      = (int*)p;              p += N_NODES * 4;
    int*   rowstart = (int*)p;              p += (N_NODES + 1) * 4;
    int*   rank     = (int*)p;              p += (size_t)E_EDGES * 4;      // 2.56 MB
    int*   bsum     = (int*)p;              p += NB * 4;
    int*   boff     = (int*)p;              p += NB * 4;
    float2* srec    = (float2*)((((uintptr_t)p) + 15) & ~(uintptr_t)15);   // 5.12 MB

    // 1) GEMM (fp32 compute, bf16 store) + zero cnt
    k_gemm<<<N_NODES / BM, 256, 0, stream>>>(x, w, out_lin, cnt);
    // 2) count + per-edge rank (only remaining scattered atomics)
    k_cnt<<<(E_EDGES + 255) / 256, 256, 0, stream>>>(ei, cnt, rank);
    // 3) 3-phase scan -> rowstart
    k_scanA<<<NB, 256, 0, stream>>>(cnt, bsum);
    k_scanB<<<1, 256, 0, stream>>>(bsum, boff, rowstart);
    k_scanC<<<NB, 256, 0, stream>>>(cnt, boff, rowstart);
    // 4) atomic-free scatter into sorted records
    k_scat<<<(E_EDGES + 255) / 256, 256, 0, stream>>>(ei, ew, aw, rowstart, rank, srec);
    // 5) deg + dis from sorted records (atomic-free)
    k_degdis<<<NB, 256, 0, stream>>>(rowstart, srec, dis);
    // 6) fused pull-aggregation + bias + LN + LeakyReLU
    k_agg<<<(N_NODES + 3) / 4, 256, 0, stream>>>(rowstart, srec,
                                                 (const __hip_bfloat162*)out_lin, dis,
                                                 bias, gamma, beta, out);
}

// Round 16
// 194.189 us; speedup vs baseline: 3.5112x; 1.0881x over previous
//
#include <hip/hip_runtime.h>
#include <hip/hip_bf16.h>
#include <math.h>

#define N_NODES 40000
#define E_EDGES 640000
#define D 128
#define LN_EPS 1e-5f
#define LEAKY 0.2f
#define NB 157   // ceil(40000/256)

// ---------------- GEMM: out_lin[N,128] = bf16(x[N,128] @ w[128,128]); also zeros cnt ----------------
#define BM 32
__global__ __launch_bounds__(256) void k_gemm(const float* __restrict__ x,
                                              const float* __restrict__ w,
                                              __hip_bfloat16* __restrict__ outb,
                                              int* __restrict__ cnt) {
    // fused: zero cnt[] (grid is 1250 blocks ≫ NB)
    int gid = blockIdx.x * 256 + threadIdx.x;
    if (gid < N_NODES) cnt[gid] = 0;

    __shared__ float ws[128 * 128];
    __shared__ float xs[BM * 128];
    int t = threadIdx.x;

    const float4* w4 = (const float4*)w;
    float4* ws4 = (float4*)ws;
#pragma unroll
    for (int i = 0; i < 16; i++) ws4[t + i * 256] = w4[t + i * 256];

    int row0 = blockIdx.x * BM;
    const float4* x4 = (const float4*)(x + (size_t)row0 * D);
    float4* xs4 = (float4*)xs;
#pragma unroll
    for (int i = 0; i < 4; i++) xs4[t + i * 256] = x4[t + i * 256];

    __syncthreads();

    int c0 = (t & 31) * 4;
    int r0 = (t >> 5) * 4;
    float acc[4][4] = {};
#pragma unroll 4
    for (int k = 0; k < 128; k++) {
        float4 wv = *(const float4*)&ws[k * 128 + c0];
        float x0 = xs[(r0 + 0) * 128 + k];
        float x1 = xs[(r0 + 1) * 128 + k];
        float x2 = xs[(r0 + 2) * 128 + k];
        float x3 = xs[(r0 + 3) * 128 + k];
        acc[0][0] += x0 * wv.x; acc[0][1] += x0 * wv.y; acc[0][2] += x0 * wv.z; acc[0][3] += x0 * wv.w;
        acc[1][0] += x1 * wv.x; acc[1][1] += x1 * wv.y; acc[1][2] += x1 * wv.z; acc[1][3] += x1 * wv.w;
        acc[2][0] += x2 * wv.x; acc[2][1] += x2 * wv.y; acc[2][2] += x2 * wv.z; acc[2][3] += x2 * wv.w;
        acc[3][0] += x3 * wv.x; acc[3][1] += x3 * wv.y; acc[3][2] += x3 * wv.z; acc[3][3] += x3 * wv.w;
    }
#pragma unroll
    for (int i = 0; i < 4; i++) {
        int row = row0 + r0 + i;
        __hip_bfloat162 p0 = __float22bfloat162_rn(make_float2(acc[i][0], acc[i][1]));
        __hip_bfloat162 p1 = __float22bfloat162_rn(make_float2(acc[i][2], acc[i][3]));
        uint2 pk;
        pk.x = *(unsigned int*)&p0;
        pk.y = *(unsigned int*)&p1;
        *(uint2*)&outb[(size_t)row * D + c0] = pk;
    }
}

// ---------------- count + stable rank: rank[e] = cnt[row]++ ----------------
__global__ __launch_bounds__(256) void k_cnt(const int* __restrict__ ei,
                                             int* __restrict__ cnt,
                                             int* __restrict__ rank) {
    int e = blockIdx.x * 256 + threadIdx.x;
    if (e >= E_EDGES) return;
    rank[e] = atomicAdd(&cnt[ei[e]], 1);
}

// ---------------- 3-phase device-wide exclusive scan of cnt ----------------
__global__ __launch_bounds__(256) void k_scanA(const int* __restrict__ cnt,
                                               int* __restrict__ bsum) {
    __shared__ int red[256];
    int t = threadIdx.x;
    int i = blockIdx.x * 256 + t;
    red[t] = (i < N_NODES) ? cnt[i] : 0;
    __syncthreads();
    for (int off = 128; off > 0; off >>= 1) {
        if (t < off) red[t] += red[t + off];
        __syncthreads();
    }
    if (t == 0) bsum[blockIdx.x] = red[0];
}

__global__ __launch_bounds__(256) void k_scanB(const int* __restrict__ bsum,
                                               int* __restrict__ boff,
                                               int* __restrict__ rowstart) {
    __shared__ int s[256];
    int t = threadIdx.x;
    int v = (t < NB) ? bsum[t] : 0;
    s[t] = v;
    __syncthreads();
    for (int off = 1; off < 256; off <<= 1) {
        int u = (t >= off) ? s[t - off] : 0;
        __syncthreads();
        s[t] += u;
        __syncthreads();
    }
    if (t < NB) boff[t] = s[t] - v;   // exclusive
    if (t == 0) rowstart[N_NODES] = E_EDGES;
}

__global__ __launch_bounds__(256) void k_scanC(const int* __restrict__ cnt,
                                               const int* __restrict__ boff,
                                               int* __restrict__ rowstart) {
    __shared__ int s[256];
    int t = threadIdx.x;
    int i = blockIdx.x * 256 + t;
    int v = (i < N_NODES) ? cnt[i] : 0;
    s[t] = v;
    __syncthreads();
    for (int off = 1; off < 256; off <<= 1) {
        int u = (t >= off) ? s[t - off] : 0;
        __syncthreads();
        s[t] += u;
        __syncthreads();
    }
    if (i < N_NODES) rowstart[i] = boff[blockIdx.x] + s[t] - v;
}

// ---------------- atomic-free scatter into row-sorted records ----------------
// srec[rowstart[r] + rank[e]] = (col_bits, ew*sig)
__global__ __launch_bounds__(256) void k_scat(const int* __restrict__ ei,
                                              const float* __restrict__ ew,
                                              const float* __restrict__ aw,
                                              const int* __restrict__ rowstart,
                                              const int* __restrict__ rank,
                                              float2* __restrict__ srec) {
    int e = blockIdx.x * 256 + threadIdx.x;
    if (e >= E_EDGES) return;
    float sig = 1.f / (1.f + __expf(-aw[0]));
    int r = ei[e];
    int c = ei[E_EDGES + e];
    int slot = rowstart[r] + rank[e];
    srec[slot] = make_float2(__int_as_float(c), ew[e] * sig);
}

// ---------------- deg from sorted records (atomic-free) + dis = rsqrt ----------------
__global__ __launch_bounds__(256) void k_degdis(const int* __restrict__ rowstart,
                                                const float2* __restrict__ srec,
                                                float* __restrict__ dis) {
    int i = blockIdx.x * 256 + threadIdx.x;
    if (i >= N_NODES) return;
    int s = rowstart[i];
    int e = rowstart[i + 1];
    float d = 0.f;
    for (int j = s; j < e; j++) d += srec[j].y;
    dis[i] = (d > 0.f) ? rsqrtf(d) : 0.f;
}

// ---------------- pull-aggregation + bias + LN + LeakyReLU, one wave per row ----------------
// 4-edge unrolled gather loop: 4 independent srec loads -> 4 independent
// gathers + 4 dis loads in flight (MLP ~9 vs ~2) to break the
// srec->col->gather dependent-latency chain (round-10 diagnosis).
__global__ __launch_bounds__(256) void k_agg(const int* __restrict__ rowstart,
                                             const float2* __restrict__ srec,
                                             const __hip_bfloat162* __restrict__ lin2,
                                             const float* __restrict__ dis,
                                             const float* __restrict__ bias,
                                             const float* __restrict__ gamma,
                                             const float* __restrict__ beta,
                                             float* __restrict__ out) {
    int w = (blockIdx.x * 256 + threadIdx.x) >> 6;
    int lane = threadIdx.x & 63;
    if (w >= N_NODES) return;
    int s = __builtin_amdgcn_readfirstlane(rowstart[w]);
    int e = __builtin_amdgcn_readfirstlane(rowstart[w + 1]);
    float dr = dis[w];

    float2 acc = make_float2(0.f, 0.f);
    int i = s;
    for (; i + 4 <= e; i += 4) {
        float2 r0 = srec[i];
        float2 r1 = srec[i + 1];
        float2 r2 = srec[i + 2];
        float2 r3 = srec[i + 3];
        int c0 = __float_as_int(r0.x);
        int c1 = __float_as_int(r1.x);
        int c2 = __float_as_int(r2.x);
        int c3 = __float_as_int(r3.x);
        __hip_bfloat162 t0 = lin2[(size_t)c0 * 64 + lane];
        __hip_bfloat162 t1 = lin2[(size_t)c1 * 64 + lane];
        __hip_bfloat162 t2 = lin2[(size_t)c2 * 64 + lane];
        __hip_bfloat162 t3 = lin2[(size_t)c3 * 64 + lane];
        float v0 = r0.y * dis[c0];
        float v1 = r1.y * dis[c1];
        float v2 = r2.y * dis[c2];
        float v3 = r3.y * dis[c3];
        float2 f0 = __bfloat1622float2(t0);
        float2 f1 = __bfloat1622float2(t1);
        float2 f2 = __bfloat1622float2(t2);
        float2 f3 = __bfloat1622float2(t3);
        acc.x += f0.x * v0; acc.y += f0.y * v0;
        acc.x += f1.x * v1; acc.y += f1.y * v1;
        acc.x += f2.x * v2; acc.y += f2.y * v2;
        acc.x += f3.x * v3; acc.y += f3.y * v3;
    }
    for (; i < e; i++) {
        float2 rec = srec[i];
        int c = __float_as_int(rec.x);
        float v = rec.y * dis[c];
        __hip_bfloat162 t = lin2[(size_t)c * 64 + lane];
        float2 tf = __bfloat1622float2(t);
        acc.x += tf.x * v;
        acc.y += tf.y * v;
    }
    acc.x *= dr; acc.y *= dr;

    float2 b = *(const float2*)&bias[lane * 2];
    acc.x += b.x; acc.y += b.y;

    float sm = acc.x + acc.y;
#pragma unroll
    for (int m = 1; m < 64; m <<= 1) sm += __shfl_xor(sm, m);
    float mu = sm * (1.f / 128.f);

    float dx = acc.x - mu, dy = acc.y - mu;
    float q = dx * dx + dy * dy;
#pragma unroll
    for (int m = 1; m < 64; m <<= 1) q += __shfl_xor(q, m);
    float rstd = rsqrtf(q * (1.f / 128.f) + LN_EPS);

    float2 g  = *(const float2*)&gamma[lane * 2];
    float2 be = *(const float2*)&beta[lane * 2];
    float y0 = dx * rstd * g.x + be.x;
    float y1 = dy * rstd * g.y + be.y;
    y0 = (y0 >= 0.f) ? y0 : LEAKY * y0;
    y1 = (y1 >= 0.f) ? y1 : LEAKY * y1;
    *(float2*)&out[(size_t)w * D + lane * 2] = make_float2(y0, y1);
}

extern "C" void kernel_launch(void* const* d_in, const int* in_sizes, int n_in,
                              void* d_out, int out_size, void* d_ws, size_t ws_size,
                              hipStream_t stream) {
    const float* x      = (const float*)d_in[0];
    const int*   ei     = (const int*)d_in[1];
    const float* ew     = (const float*)d_in[2];
    const float* w      = (const float*)d_in[3];
    const float* aw     = (const float*)d_in[4];
    const float* bias   = (const float*)d_in[5];
    const float* gamma  = (const float*)d_in[6];
    const float* beta   = (const float*)d_in[7];
    float* out = (float*)d_out;

    // workspace layout
    char* p = (char*)d_ws;
    __hip_bfloat16* out_lin = (__hip_bfloat16*)p; p += (size_t)N_NODES * D * 2; // 10.24 MB
    float* dis      = (float*)p;            p += N_NODES * 4;
    int*   cnt      = (int*)p;              p += N_NODES * 4;
    int*   rowstart = (int*)p;              p += (N_NODES + 1) * 4;
    int*   rank     = (int*)p;              p += (size_t)E_EDGES * 4;      // 2.56 MB
    int*   bsum     = (int*)p;              p += NB * 4;
    int*   boff     = (int*)p;              p += NB * 4;
    float2* srec    = (float2*)((((uintptr_t)p) + 15) & ~(uintptr_t)15);   // 5.12 MB

    // 1) GEMM (fp32 compute, bf16 store) + zero cnt
    k_gemm<<<N_NODES / BM, 256, 0, stream>>>(x, w, out_lin, cnt);
    // 2) count + per-edge rank (only remaining scattered atomics)
    k_cnt<<<(E_EDGES + 255) / 256, 256, 0, stream>>>(ei, cnt, rank);
    // 3) 3-phase scan -> rowstart
    k_scanA<<<NB, 256, 0, stream>>>(cnt, bsum);
    k_scanB<<<1, 256, 0, stream>>>(bsum, boff, rowstart);
    k_scanC<<<NB, 256, 0, stream>>>(cnt, boff, rowstart);
    // 4) atomic-free scatter into sorted records
    k_scat<<<(E_EDGES + 255) / 256, 256, 0, stream>>>(ei, ew, aw, rowstart, rank, srec);
    // 5) deg + dis from sorted records (atomic-free)
    k_degdis<<<NB, 256, 0, stream>>>(rowstart, srec, dis);
    // 6) fused pull-aggregation + bias + LN + LeakyReLU
    k_agg<<<(N_NODES + 3) / 4, 256, 0, stream>>>(rowstart, srec,
                                                 (const __hip_bfloat162*)out_lin, dis,
                                                 bias, gamma, beta, out);
}

// Round 18
// 178.007 us; speedup vs baseline: 3.8303x; 1.0909x over previous
//
#include <hip/hip_runtime.h>
#include <hip/hip_bf16.h>
#include <math.h>

#define N_NODES 40000
#define E_EDGES 640000
#define D 128
#define LN_EPS 1e-5f
#define LEAKY 0.2f
#define NB 157   // ceil(40000/256)

// ---------------- zero cnt[N] (must complete before gemm+cnt atomics) ----------------
__global__ __launch_bounds__(256) void k_zero(int* __restrict__ cnt) {
    int i = blockIdx.x * 256 + threadIdx.x;
    if (i < N_NODES) cnt[i] = 0;
}

// ---------------- fused GEMM + edge-count ----------------
// GEMM: out_lin[N,128] = bf16(x[N,128] @ w[128,128])
// + each block counts 512 edges (atomics overlap with GEMM staging/compute;
//   rank stored after C-write so the atomic latency hides under the tile math).
#define BM 32
__global__ __launch_bounds__(256) void k_gemmcnt(const float* __restrict__ x,
                                                 const float* __restrict__ w,
                                                 const int* __restrict__ ei,
                                                 __hip_bfloat16* __restrict__ outb,
                                                 int* __restrict__ cnt,
                                                 int* __restrict__ rank) {
    int t = threadIdx.x;
    int blk = blockIdx.x;

    // --- edge phase: issue scattered atomics early (1250 blocks x 512 edges = 640000) ---
    int e0 = blk * 512 + t;
    int e1 = e0 + 256;
    int er0 = ei[e0];
    int er1 = ei[e1];
    int k0 = atomicAdd(&cnt[er0], 1);
    int k1 = atomicAdd(&cnt[er1], 1);

    __shared__ float ws[128 * 128];
    __shared__ float xs[BM * 128];

    const float4* w4 = (const float4*)w;
    float4* ws4 = (float4*)ws;
#pragma unroll
    for (int i = 0; i < 16; i++) ws4[t + i * 256] = w4[t + i * 256];

    int row0 = blk * BM;
    const float4* x4 = (const float4*)(x + (size_t)row0 * D);
    float4* xs4 = (float4*)xs;
#pragma unroll
    for (int i = 0; i < 4; i++) xs4[t + i * 256] = x4[t + i * 256];

    __syncthreads();

    int c0 = (t & 31) * 4;
    int r0 = (t >> 5) * 4;
    float acc[4][4] = {};
#pragma unroll 4
    for (int k = 0; k < 128; k++) {
        float4 wv = *(const float4*)&ws[k * 128 + c0];
        float x0 = xs[(r0 + 0) * 128 + k];
        float x1 = xs[(r0 + 1) * 128 + k];
        float x2 = xs[(r0 + 2) * 128 + k];
        float x3 = xs[(r0 + 3) * 128 + k];
        acc[0][0] += x0 * wv.x; acc[0][1] += x0 * wv.y; acc[0][2] += x0 * wv.z; acc[0][3] += x0 * wv.w;
        acc[1][0] += x1 * wv.x; acc[1][1] += x1 * wv.y; acc[1][2] += x1 * wv.z; acc[1][3] += x1 * wv.w;
        acc[2][0] += x2 * wv.x; acc[2][1] += x2 * wv.y; acc[2][2] += x2 * wv.z; acc[2][3] += x2 * wv.w;
        acc[3][0] += x3 * wv.x; acc[3][1] += x3 * wv.y; acc[3][2] += x3 * wv.z; acc[3][3] += x3 * wv.w;
    }
#pragma unroll
    for (int i = 0; i < 4; i++) {
        int row = row0 + r0 + i;
        __hip_bfloat162 p0 = __float22bfloat162_rn(make_float2(acc[i][0], acc[i][1]));
        __hip_bfloat162 p1 = __float22bfloat162_rn(make_float2(acc[i][2], acc[i][3]));
        uint2 pk;
        pk.x = *(unsigned int*)&p0;
        pk.y = *(unsigned int*)&p1;
        *(uint2*)&outb[(size_t)row * D + c0] = pk;
    }

    // --- edge phase epilogue: ranks (atomic results long since returned) ---
    rank[e0] = k0;
    rank[e1] = k1;
}

// ---------------- 3-phase device-wide exclusive scan of cnt ----------------
__global__ __launch_bounds__(256) void k_scanA(const int* __restrict__ cnt,
                                               int* __restrict__ bsum) {
    __shared__ int red[256];
    int t = threadIdx.x;
    int i = blockIdx.x * 256 + t;
    red[t] = (i < N_NODES) ? cnt[i] : 0;
    __syncthreads();
    for (int off = 128; off > 0; off >>= 1) {
        if (t < off) red[t] += red[t + off];
        __syncthreads();
    }
    if (t == 0) bsum[blockIdx.x] = red[0];
}

__global__ __launch_bounds__(256) void k_scanB(const int* __restrict__ bsum,
                                               int* __restrict__ boff,
                                               int* __restrict__ rowstart) {
    __shared__ int s[256];
    int t = threadIdx.x;
    int v = (t < NB) ? bsum[t] : 0;
    s[t] = v;
    __syncthreads();
    for (int off = 1; off < 256; off <<= 1) {
        int u = (t >= off) ? s[t - off] : 0;
        __syncthreads();
        s[t] += u;
        __syncthreads();
    }
    if (t < NB) boff[t] = s[t] - v;   // exclusive
    if (t == 0) rowstart[N_NODES] = E_EDGES;
}

__global__ __launch_bounds__(256) void k_scanC(const int* __restrict__ cnt,
                                               const int* __restrict__ boff,
                                               int* __restrict__ rowstart) {
    __shared__ int s[256];
    int t = threadIdx.x;
    int i = blockIdx.x * 256 + t;
    int v = (i < N_NODES) ? cnt[i] : 0;
    s[t] = v;
    __syncthreads();
    for (int off = 1; off < 256; off <<= 1) {
        int u = (t >= off) ? s[t - off] : 0;
        __syncthreads();
        s[t] += u;
        __syncthreads();
    }
    if (i < N_NODES) rowstart[i] = boff[blockIdx.x] + s[t] - v;
}

// ---------------- atomic-free scatter into row-sorted records ----------------
// srec[rowstart[r] + rank[e]] = (col_bits, ew*sig)
__global__ __launch_bounds__(256) void k_scat(const int* __restrict__ ei,
                                              const float* __restrict__ ew,
                                              const float* __restrict__ aw,
                                              const int* __restrict__ rowstart,
                                              const int* __restrict__ rank,
                                              float2* __restrict__ srec) {
    int e = blockIdx.x * 256 + threadIdx.x;
    if (e >= E_EDGES) return;
    float sig = 1.f / (1.f + __expf(-aw[0]));
    int r = ei[e];
    int c = ei[E_EDGES + e];
    int slot = rowstart[r] + rank[e];
    srec[slot] = make_float2(__int_as_float(c), ew[e] * sig);
}

// ---------------- deg from sorted records: 4 lanes per row ----------------
__global__ __launch_bounds__(256) void k_degdis(const int* __restrict__ rowstart,
                                                const float2* __restrict__ srec,
                                                float* __restrict__ dis) {
    int t = threadIdx.x;
    int row = (blockIdx.x * 256 + t) >> 2;   // 4 lanes per row
    int sub = t & 3;
    if (row >= N_NODES) return;
    int s = rowstart[row];
    int e = rowstart[row + 1];
    float d = 0.f;
    for (int j = s + sub; j < e; j += 4) d += srec[j].y;
    d += __shfl_xor(d, 1);
    d += __shfl_xor(d, 2);
    if (sub == 0) dis[row] = (d > 0.f) ? rsqrtf(d) : 0.f;
}

// ---------------- pull-aggregation + bias + LN + LeakyReLU, one wave per row ----------------
// 8-edge unrolled gather loop (round-16 confirmed latency-bound; deeper MLP).
__global__ __launch_bounds__(256) void k_agg(const int* __restrict__ rowstart,
                                             const float2* __restrict__ srec,
                                             const __hip_bfloat162* __restrict__ lin2,
                                             const float* __restrict__ dis,
                                             const float* __restrict__ bias,
                                             const float* __restrict__ gamma,
                                             const float* __restrict__ beta,
                                             float* __restrict__ out) {
    int w = (blockIdx.x * 256 + threadIdx.x) >> 6;
    int lane = threadIdx.x & 63;
    if (w >= N_NODES) return;
    int s = __builtin_amdgcn_readfirstlane(rowstart[w]);
    int e = __builtin_amdgcn_readfirstlane(rowstart[w + 1]);
    float dr = dis[w];

    float2 acc = make_float2(0.f, 0.f);
    int i = s;
    for (; i + 8 <= e; i += 8) {
        float2 rr[8];
#pragma unroll
        for (int u = 0; u < 8; u++) rr[u] = srec[i + u];
        int cc[8];
#pragma unroll
        for (int u = 0; u < 8; u++) cc[u] = __float_as_int(rr[u].x);
        __hip_bfloat162 tt[8];
#pragma unroll
        for (int u = 0; u < 8; u++) tt[u] = lin2[(size_t)cc[u] * 64 + lane];
        float vv[8];
#pragma unroll
        for (int u = 0; u < 8; u++) vv[u] = rr[u].y * dis[cc[u]];
#pragma unroll
        for (int u = 0; u < 8; u++) {
            float2 f = __bfloat1622float2(tt[u]);
            acc.x += f.x * vv[u];
            acc.y += f.y * vv[u];
        }
    }
    for (; i + 4 <= e; i += 4) {
        float2 r0 = srec[i];
        float2 r1 = srec[i + 1];
        float2 r2 = srec[i + 2];
        float2 r3 = srec[i + 3];
        int c0 = __float_as_int(r0.x);
        int c1 = __float_as_int(r1.x);
        int c2 = __float_as_int(r2.x);
        int c3 = __float_as_int(r3.x);
        __hip_bfloat162 t0 = lin2[(size_t)c0 * 64 + lane];
        __hip_bfloat162 t1 = lin2[(size_t)c1 * 64 + lane];
        __hip_bfloat162 t2 = lin2[(size_t)c2 * 64 + lane];
        __hip_bfloat162 t3 = lin2[(size_t)c3 * 64 + lane];
        float v0 = r0.y * dis[c0];
        float v1 = r1.y * dis[c1];
        float v2 = r2.y * dis[c2];
        float v3 = r3.y * dis[c3];
        float2 f0 = __bfloat1622float2(t0);
        float2 f1 = __bfloat1622float2(t1);
        float2 f2 = __bfloat1622float2(t2);
        float2 f3 = __bfloat1622float2(t3);
        acc.x += f0.x * v0; acc.y += f0.y * v0;
        acc.x += f1.x * v1; acc.y += f1.y * v1;
        acc.x += f2.x * v2; acc.y += f2.y * v2;
        acc.x += f3.x * v3; acc.y += f3.y * v3;
    }
    for (; i < e; i++) {
        float2 rec = srec[i];
        int c = __float_as_int(rec.x);
        float v = rec.y * dis[c];
        __hip_bfloat162 t = lin2[(size_t)c * 64 + lane];
        float2 tf = __bfloat1622float2(t);
        acc.x += tf.x * v;
        acc.y += tf.y * v;
    }
    acc.x *= dr; acc.y *= dr;

    float2 b = *(const float2*)&bias[lane * 2];
    acc.x += b.x; acc.y += b.y;

    float sm = acc.x + acc.y;
#pragma unroll
    for (int m = 1; m < 64; m <<= 1) sm += __shfl_xor(sm, m);
    float mu = sm * (1.f / 128.f);

    float dx = acc.x - mu, dy = acc.y - mu;
    float q = dx * dx + dy * dy;
#pragma unroll
    for (int m = 1; m < 64; m <<= 1) q += __shfl_xor(q, m);
    float rstd = rsqrtf(q * (1.f / 128.f) + LN_EPS);

    float2 g  = *(const float2*)&gamma[lane * 2];
    float2 be = *(const float2*)&beta[lane * 2];
    float y0 = dx * rstd * g.x + be.x;
    float y1 = dy * rstd * g.y + be.y;
    y0 = (y0 >= 0.f) ? y0 : LEAKY * y0;
    y1 = (y1 >= 0.f) ? y1 : LEAKY * y1;
    *(float2*)&out[(size_t)w * D + lane * 2] = make_float2(y0, y1);
}

extern "C" void kernel_launch(void* const* d_in, const int* in_sizes, int n_in,
                              void* d_out, int out_size, void* d_ws, size_t ws_size,
                              hipStream_t stream) {
    const float* x      = (const float*)d_in[0];
    const int*   ei     = (const int*)d_in[1];
    const float* ew     = (const float*)d_in[2];
    const float* w      = (const float*)d_in[3];
    const float* aw     = (const float*)d_in[4];
    const float* bias   = (const float*)d_in[5];
    const float* gamma  = (const float*)d_in[6];
    const float* beta   = (const float*)d_in[7];
    float* out = (float*)d_out;

    // workspace layout
    char* p = (char*)d_ws;
    __hip_bfloat16* out_lin = (__hip_bfloat16*)p; p += (size_t)N_NODES * D * 2; // 10.24 MB
    float* dis      = (float*)p;            p += N_NODES * 4;
    int*   cnt      = (int*)p;              p += N_NODES * 4;
    int*   rowstart = (int*)p;              p += (N_NODES + 1) * 4;
    int*   rank     = (int*)p;              p += (size_t)E_EDGES * 4;      // 2.56 MB
    int*   bsum     = (int*)p;              p += NB * 4;
    int*   boff     = (int*)p;              p += NB * 4;
    float2* srec    = (float2*)((((uintptr_t)p) + 15) & ~(uintptr_t)15);   // 5.12 MB

    // 1) zero cnt (must precede fused atomics)
    k_zero<<<NB, 256, 0, stream>>>(cnt);
    // 2) fused GEMM (fp32 compute, bf16 store) + edge count/rank
    k_gemmcnt<<<N_NODES / BM, 256, 0, stream>>>(x, w, ei, out_lin, cnt, rank);
    // 3) 3-phase scan -> rowstart
    k_scanA<<<NB, 256, 0, stream>>>(cnt, bsum);
    k_scanB<<<1, 256, 0, stream>>>(bsum, boff, rowstart);
    k_scanC<<<NB, 256, 0, stream>>>(cnt, boff, rowstart);
    // 4) atomic-free scatter into sorted records
    k_scat<<<(E_EDGES + 255) / 256, 256, 0, stream>>>(ei, ew, aw, rowstart, rank, srec);
    // 5) deg + dis from sorted records (4 lanes/row)
    k_degdis<<<(N_NODES * 4 + 255) / 256, 256, 0, stream>>>(rowstart, srec, dis);
    // 6) fused pull-aggregation + bias + LN + LeakyReLU
    k_agg<<<(N_NODES + 3) / 4, 256, 0, stream>>>(rowstart, srec,
                                                 (const __hip_bfloat162*)out_lin, dis,
                                                 bias, gamma, beta, out);
}